// Round 4
// baseline (495.140 us; speedup 1.0000x reference)
//
#include <hip/hip_runtime.h>

// Problem constants (fixed by setup_inputs in the reference):
//   k,v: [B=2, C=128, Hc=48, Wc=48] fp32; NUM_HEADS=8 -> hd=16
//   WINDOW=5, DILATION=1 -> K=25 offsets, r=2
//   query grid 96x96, scale_factor=2
// Outputs (flat, concatenated):
//   out0 k_nb  [2,8,25,16,96,96]  = 58,982,400 floats
//   out1 v_nb  [2,8,25,16,96,96]  = 58,982,400 floats
//   out2 mask  [2,8,25,96,96]     =  3,686,400 floats (bool -> 0.0/1.0)

#define KV_ELEMS  58982400LL
#define MASK_OFF  117964800LL

typedef float f32x4 __attribute__((ext_vector_type(4)));

// Fill-mimicking coherent sweep.
// 1800 blocks x 256 = 460,800 threads — fully resident (28 waves/CU), like
// the harness fill's grid-stride. Thread owns fixed (kk, d0, y, x4); loops
// z = 0..15 handling channels d = d0 and d0+8. Per z-iteration the WHOLE
// grid writes one dense 14.7 MB slab of out_k and out_v (float4 window
// [z*921600, (z+1)*921600)), sweeping forward in phase -> DRAM row locality
// matching the 6.3 TB/s fill. Index math + validity computed once/thread.
__global__ __launch_bounds__(256) void sweep_kernel(
    const float* __restrict__ kp, const float* __restrict__ vp,
    float* __restrict__ out_k, float* __restrict__ out_v,
    float* __restrict__ out_m) {
    const int tid = blockIdx.x * 256 + threadIdx.x;   // [0, 460800)
    const int x4 = tid % 24;
    int t = tid / 24;
    const int y  = t % 96;  t /= 96;
    const int d0 = t % 8;                 // d in {d0, d0+8}; wave-uniform
    const int kk = t / 8;                 // 0..24; wave-uniform

    const int kq = kk / 5;
    const int dy = kq - 2;
    const int dx = kk - kq * 5 - 2;

    const int yy  = (y >> 1) + dy;
    const bool vy = (unsigned)yy < 48u;
    const int xc0 = 2 * x4 + dx;
    const bool v0 = vy && ((unsigned)xc0 < 48u);
    const bool v1 = vy && ((unsigned)(xc0 + 1) < 48u);

    const int yc = vy ? yy : 0;
    const int x0 = min(max(xc0, 0), 47);
    const int x1 = min(max(xc0 + 1, 0), 47);

    // channel d0 source base (z adds 36864 floats; d0+8 adds 18432)
    int base = (d0 * 48 + yc) * 48;
    // out float4 index for (z=0, d=d0): kk*36864 + d0*2304 + y*24 + x4
    int o = tid + kk * 18432;

    const bool do_mask = (d0 == 0);       // wave-uniform (2304 % 64 == 0)
    const int mbase = tid - kk * 16128;   // mask f4 idx at z=0 (when d0==0)
    f32x4 om;
    if (do_mask) {
        const float m0 = v0 ? 1.0f : 0.0f;
        const float m1 = v1 ? 1.0f : 0.0f;
        om = (f32x4){m0, m0, m1, m1};
    }

#pragma unroll 2
    for (int z = 0; z < 16; ++z) {
        const int b1 = base;
        const int b2 = base + 18432;
        float ka0 = kp[b1 + x0], ka1 = kp[b1 + x1];
        float kb0 = kp[b2 + x0], kb1 = kp[b2 + x1];
        float va0 = vp[b1 + x0], va1 = vp[b1 + x1];
        float vb0 = vp[b2 + x0], vb1 = vp[b2 + x1];
        ka0 = v0 ? ka0 : 0.0f;  ka1 = v1 ? ka1 : 0.0f;
        kb0 = v0 ? kb0 : 0.0f;  kb1 = v1 ? kb1 : 0.0f;
        va0 = v0 ? va0 : 0.0f;  va1 = v1 ? va1 : 0.0f;
        vb0 = v0 ? vb0 : 0.0f;  vb1 = v1 ? vb1 : 0.0f;

        f32x4 oka = {ka0, ka0, ka1, ka1};
        f32x4 okb = {kb0, kb0, kb1, kb1};
        f32x4 ova = {va0, va0, va1, va1};
        f32x4 ovb = {vb0, vb0, vb1, vb1};
        __builtin_nontemporal_store(oka, reinterpret_cast<f32x4*>(out_k) + o);
        __builtin_nontemporal_store(okb, reinterpret_cast<f32x4*>(out_k) + o + 18432);
        __builtin_nontemporal_store(ova, reinterpret_cast<f32x4*>(out_v) + o);
        __builtin_nontemporal_store(ovb, reinterpret_cast<f32x4*>(out_v) + o + 18432);
        if (do_mask)
            __builtin_nontemporal_store(
                om, reinterpret_cast<f32x4*>(out_m) + mbase + z * 57600);

        base += 36864;
        o += 921600;
    }
}

extern "C" void kernel_launch(void* const* d_in, const int* in_sizes, int n_in,
                              void* d_out, int out_size, void* d_ws, size_t ws_size,
                              hipStream_t stream) {
    const float* k = (const float*)d_in[0];
    const float* v = (const float*)d_in[1];
    float* out = (float*)d_out;
    float* out_k = out;
    float* out_v = out + KV_ELEMS;
    float* out_m = out + MASK_OFF;

    sweep_kernel<<<1800, 256, 0, stream>>>(k, v, out_k, out_v, out_m);
}

// Round 5
// 487.978 us; speedup vs baseline: 1.0147x; 1.0147x over previous
//
#include <hip/hip_runtime.h>

// Problem constants (fixed by setup_inputs in the reference):
//   k,v: [B=2, C=128, Hc=48, Wc=48] fp32; NUM_HEADS=8 -> hd=16
//   WINDOW=5, DILATION=1 -> K=25 offsets, r=2
//   query grid 96x96, scale_factor=2
// Outputs (flat, concatenated):
//   out0 k_nb  [2,8,25,16,96,96]  = 58,982,400 floats
//   out1 v_nb  [2,8,25,16,96,96]  = 58,982,400 floats
//   out2 mask  [2,8,25,96,96]     =  3,686,400 floats (bool -> 0.0/1.0)

#define KV_F4    14745600   // float4s in one kv tensor
#define TOT_F4   30412800   // float4s in the whole output

typedef float f32x4 __attribute__((ext_vector_type(4)));

// Single linear sweep over the ENTIRE output, byte-identical access pattern
// to the harness fill that sustains 6.3 TB/s: one float4 store per thread at
// out[f], f = blockIdx.x*256 + tx, waves write 1024B-contiguous, whole grid
// advances linearly. Region boundaries (14745600, 29491200) are multiples of
// 256 -> region & source-pointer selection are block-uniform (scalar).
__global__ __launch_bounds__(256) void linear_sweep_kernel(
    const float* __restrict__ kp, const float* __restrict__ vp,
    float* __restrict__ out) {
    const int f = blockIdx.x * 256 + threadIdx.x;   // float4 index < 30412800

    if (f < 2 * KV_F4) {
        // ---- k_nb / v_nb region (block-uniform choice) ----
        const bool is_k = (f < KV_F4);
        const float* __restrict__ src = is_k ? kp : vp;
        const int f2 = is_k ? f : f - KV_F4;
        // f2 = ((((b*8+h)*25+kk)*16+d)*96+y)*24 + x4
        const int x4 = f2 % 24;  int t = f2 / 24;
        const int y  = t % 96;   t /= 96;
        const int d  = t % 16;   t /= 16;
        const int kk = t % 25;   t /= 25;      // t now = b*8+h in 0..15
        const int kq = kk / 5;
        const int dy = kq - 2;
        const int dx = kk - kq * 5 - 2;

        const int yy  = (y >> 1) + dy;
        const bool vy = (unsigned)yy < 48u;
        const int xc0 = 2 * x4 + dx;
        const int xc1 = xc0 + 1;
        const bool v0 = vy && ((unsigned)xc0 < 48u);
        const bool v1 = vy && ((unsigned)xc1 < 48u);

        const int yc = vy ? yy : 0;
        const int x0 = min(max(xc0, 0), 47);
        const int x1 = min(max(xc1, 0), 47);

        const int base = ((t * 16 + d) * 48 + yc) * 48;
        float a0 = src[base + x0];
        float a1 = src[base + x1];
        a0 = v0 ? a0 : 0.0f;
        a1 = v1 ? a1 : 0.0f;
        f32x4 o4 = {a0, a0, a1, a1};
        __builtin_nontemporal_store(o4, reinterpret_cast<f32x4*>(out) + f);
    } else {
        // ---- mask region ----
        const int f2 = f - 2 * KV_F4;          // [0, 921600)
        const int x4 = f2 % 24;  int t = f2 / 24;
        const int y  = t % 96;   t /= 96;
        const int kk = t % 25;
        const int kq = kk / 5;
        const int dy = kq - 2;
        const int dx = kk - kq * 5 - 2;

        const int yy  = (y >> 1) + dy;
        const bool vy = (unsigned)yy < 48u;
        const int xc0 = 2 * x4 + dx;
        const bool v0 = vy && ((unsigned)xc0 < 48u);
        const bool v1 = vy && ((unsigned)(xc0 + 1) < 48u);

        const float m0 = v0 ? 1.0f : 0.0f;
        const float m1 = v1 ? 1.0f : 0.0f;
        f32x4 o4 = {m0, m0, m1, m1};
        __builtin_nontemporal_store(o4, reinterpret_cast<f32x4*>(out) + f);
    }
}

extern "C" void kernel_launch(void* const* d_in, const int* in_sizes, int n_in,
                              void* d_out, int out_size, void* d_ws, size_t ws_size,
                              hipStream_t stream) {
    const float* k = (const float*)d_in[0];
    const float* v = (const float*)d_in[1];
    float* out = (float*)d_out;

    // 30,412,800 float4s / 256 = 118,800 blocks; one store per thread,
    // perfectly linear across the whole output allocation.
    linear_sweep_kernel<<<118800, 256, 0, stream>>>(k, v, out);
}

// Round 6
// 486.452 us; speedup vs baseline: 1.0179x; 1.0031x over previous
//
#include <hip/hip_runtime.h>

// Problem constants (fixed by setup_inputs in the reference):
//   k,v: [B=2, C=128, Hc=48, Wc=48] fp32; NUM_HEADS=8 -> hd=16
//   WINDOW=5, DILATION=1 -> K=25 offsets, r=2
//   query grid 96x96, scale_factor=2
// Outputs (flat, concatenated):
//   out0 k_nb  [2,8,25,16,96,96]  = 58,982,400 floats
//   out1 v_nb  [2,8,25,16,96,96]  = 58,982,400 floats
//   out2 mask  [2,8,25,96,96]     =  3,686,400 floats (bool -> 0.0/1.0)

#define KV_ELEMS  58982400LL
#define MASK_OFF  117964800LL

typedef float f32x4 __attribute__((ext_vector_type(4)));

// LDS-staged expansion: global loads fully decoupled from the store stream.
// Blocks 0..255:   k, plane p = z*16+d   (z = b*8+h)
// Blocks 256..511: v, plane p-256
//   Stage 48x48 fp32 plane (9.2 KB) into LDS once, then stream 25 kk-variants
//   of the 96x96 expansion: 225 float4 stores/thread fed by LDS reads only
//   (no vmcnt dependency in the store loop). Stores are 1024B/wave contiguous,
//   linear within each (z,kk,d) 147KB region.
// Blocks 512..961: mask (450 blocks x 2048 f4), pure compute -> store.
__global__ __launch_bounds__(256) void expand_lds_kernel(
    const float* __restrict__ kp, const float* __restrict__ vp,
    float* __restrict__ out_k, float* __restrict__ out_v,
    float* __restrict__ out_m) {
    const int bid = blockIdx.x;
    const int tid = threadIdx.x;

    __shared__ float S[2304];                 // 48x48, row stride 48

    if (bid < 512) {
        const bool is_k = bid < 256;
        const int p = is_k ? bid : bid - 256; // 0..255 = z*16+d
        const int z = p >> 4;
        const int d = p & 15;
        const float* __restrict__ src = is_k ? kp : vp;
        float* __restrict__ dst = is_k ? out_k : out_v;

        // one coalesced pass: 576 float4s
        const f32x4* sp = reinterpret_cast<const f32x4*>(src) + p * 576;
        f32x4* Sf4 = reinterpret_cast<f32x4*>(S);
        Sf4[tid]       = sp[tid];
        Sf4[tid + 256] = sp[tid + 256];
        if (tid < 64) Sf4[tid + 512] = sp[tid + 512];
        __syncthreads();

        f32x4* dstf4 = reinterpret_cast<f32x4*>(dst);
        const int obase = (z * 25 * 16 + d) * 2304;   // f4 index for kk=0

        for (int kk = 0; kk < 25; ++kk) {
            const int kq = kk / 5;                    // wave-uniform -> scalar
            const int dy = kq - 2;
            const int dx = kk - kq * 5 - 2;
            const int ob = obase + kk * (16 * 2304);
#pragma unroll
            for (int j = 0; j < 9; ++j) {
                const int idx = j * 256 + tid;        // [0, 2304)
                const int y   = idx / 24;
                const int x4  = idx - y * 24;
                const int yy  = (y >> 1) + dy;
                const bool vy = (unsigned)yy < 48u;
                const int xc0 = 2 * x4 + dx;
                const bool v0 = vy && ((unsigned)xc0 < 48u);
                const bool v1 = vy && ((unsigned)(xc0 + 1) < 48u);
                const int rb = (vy ? yy : 0) * 48;
                float a0 = S[rb + min(max(xc0, 0), 47)];
                float a1 = S[rb + min(max(xc0 + 1, 0), 47)];
                a0 = v0 ? a0 : 0.0f;
                a1 = v1 ? a1 : 0.0f;
                dstf4[ob + idx] = (f32x4){a0, a0, a1, a1};
            }
        }
    } else {
        // ---- mask: 450 blocks x 2048 f4 = 921,600 f4 ----
        const int mb = bid - 512;
        int f = mb * 2048 + tid;
        f32x4* mo = reinterpret_cast<f32x4*>(out_m);
#pragma unroll
        for (int j = 0; j < 8; ++j, f += 256) {
            const int x4 = f % 24;  int t = f / 24;
            const int y  = t % 96;  t /= 96;
            const int kk = t % 25;
            const int kq = kk / 5;
            const int dy = kq - 2;
            const int dx = kk - kq * 5 - 2;
            const int yy  = (y >> 1) + dy;
            const bool vy = (unsigned)yy < 48u;
            const int xc0 = 2 * x4 + dx;
            const bool v0 = vy && ((unsigned)xc0 < 48u);
            const bool v1 = vy && ((unsigned)(xc0 + 1) < 48u);
            const float m0 = v0 ? 1.0f : 0.0f;
            const float m1 = v1 ? 1.0f : 0.0f;
            mo[f] = (f32x4){m0, m0, m1, m1};
        }
    }
}

extern "C" void kernel_launch(void* const* d_in, const int* in_sizes, int n_in,
                              void* d_out, int out_size, void* d_ws, size_t ws_size,
                              hipStream_t stream) {
    const float* k = (const float*)d_in[0];
    const float* v = (const float*)d_in[1];
    float* out = (float*)d_out;
    float* out_k = out;
    float* out_v = out + KV_ELEMS;
    float* out_m = out + MASK_OFF;

    // 512 kv-plane blocks + 450 mask blocks
    expand_lds_kernel<<<962, 256, 0, stream>>>(k, v, out_k, out_v, out_m);
}

// Round 7
// 465.119 us; speedup vs baseline: 1.0645x; 1.0459x over previous
//
#include <hip/hip_runtime.h>

// Problem constants (fixed by setup_inputs in the reference):
//   k,v: [B=2, C=128, Hc=48, Wc=48] fp32; NUM_HEADS=8 -> hd=16
//   WINDOW=5, DILATION=1 -> K=25 offsets, r=2
//   query grid 96x96, scale_factor=2
// Outputs (flat, concatenated):
//   out0 k_nb  [2,8,25,16,96,96]  = 58,982,400 floats
//   out1 v_nb  [2,8,25,16,96,96]  = 58,982,400 floats
//   out2 mask  [2,8,25,96,96]     =  3,686,400 floats (bool -> 0.0/1.0)

#define KV_ELEMS  58982400LL
#define MASK_OFF  117964800LL

typedef float f32x4 __attribute__((ext_vector_type(4)));

// A/B experiment vs Round-2 best (468 us): IDENTICAL structure, but PLAIN
// stores instead of __builtin_nontemporal_store. The nt flag bypasses L2
// write-combining (sc0/sc1/nt); the 6.3 TB/s harness fill uses plain stores.
// Every kernel since R2 shared the nt flag — this isolates it.
//
// grid = (144, 25, 16): blockIdx.y = kk (neighbor offset), blockIdx.z = b*8+h.
// t = blockIdx.x*256 + tx in [0, 36864) decomposes as d*2304 + y*24 + x4,
// the per-(z,kk) linear float4 order of the output -> every wave's float4
// store covers 1024 contiguous bytes.
__global__ __launch_bounds__(256) void fused_expand_kernel(
    const float* __restrict__ k, const float* __restrict__ v,
    float* __restrict__ out_k, float* __restrict__ out_v,
    float* __restrict__ out_m) {
    const int t  = blockIdx.x * 256 + threadIdx.x;
    const int kk = blockIdx.y;           // 0..24
    const int z  = blockIdx.z;           // b*8+h, 0..15

    const int q  = t / 24;               // = d*96 + y
    const int x4 = t - q * 24;
    const int d  = q / 96;
    const int y  = q - d * 96;

    // wave-uniform -> scalar unit
    const int kq = kk / 5;
    const int dy = kq - 2;
    const int dx = kk - kq * 5 - 2;

    const int yy  = (y >> 1) + dy;       // coarse row + offset
    const bool vy = (unsigned)yy < 48u;
    const int xc0 = 2 * x4 + dx;         // coarse col for out x = 4*x4, 4*x4+1
    const int xc1 = xc0 + 1;             // coarse col for out x = 4*x4+2, 4*x4+3
    const bool v0 = vy && ((unsigned)xc0 < 48u);
    const bool v1 = vy && ((unsigned)xc1 < 48u);

    // Clamp indices, load unconditionally, select to 0 afterwards (branchless).
    const int yc = vy ? yy : 0;
    const int x0 = min(max(xc0, 0), 47);
    const int x1 = min(max(xc1, 0), 47);

    const int base = ((z * 16 + d) * 48 + yc) * 48;   // z*16+d = channel 0..255
    float k0 = k[base + x0];
    float k1 = k[base + x1];
    float w0 = v[base + x0];
    float w1 = v[base + x1];
    k0 = v0 ? k0 : 0.0f;
    k1 = v1 ? k1 : 0.0f;
    w0 = v0 ? w0 : 0.0f;
    w1 = v1 ? w1 : 0.0f;

    const int slice = z * 25 + kk;
    const int o = slice * 36864 + t;     // max 14,745,599 — fits int32
    reinterpret_cast<f32x4*>(out_k)[o] = (f32x4){k0, k0, k1, k1};
    reinterpret_cast<f32x4*>(out_v)[o] = (f32x4){w0, w0, w1, w1};

    if (blockIdx.x < 9) {  // block-uniform: exactly the d==0 blocks (t < 2304)
        const float m0 = v0 ? 1.0f : 0.0f;
        const float m1 = v1 ? 1.0f : 0.0f;
        reinterpret_cast<f32x4*>(out_m)[slice * 2304 + t] =
            (f32x4){m0, m0, m1, m1};
    }
}

extern "C" void kernel_launch(void* const* d_in, const int* in_sizes, int n_in,
                              void* d_out, int out_size, void* d_ws, size_t ws_size,
                              hipStream_t stream) {
    const float* k = (const float*)d_in[0];
    const float* v = (const float*)d_in[1];
    float* out = (float*)d_out;
    float* out_k = out;
    float* out_v = out + KV_ELEMS;
    float* out_m = out + MASK_OFF;

    // 36864 threads per (kk, z) slice = 144 blocks x 256; grid (144, 25, 16)
    fused_expand_kernel<<<dim3(144, 25, 16), 256, 0, stream>>>(
        k, v, out_k, out_v, out_m);
}